// Round 1
// baseline (141.662 us; speedup 1.0000x reference)
//
#include <hip/hip_runtime.h>

// SkeletonConv: out[b,o,h,w] = sum_{c,k} W[o,c,k] * x[b,c, h+(k-1)*step, w+(k-1)*dil]
// B=64, C_in=C_out=16, K=3, H=W=256, fp32. Memory-bound: 256MiB in + 256MiB out.

constexpr int CIN = 16, COUT = 16, KK = 3, H = 256, W = 256;
constexpr int WT  = 4;          // w-elements per thread (float4)
constexpr int TPR = W / WT;     // 64 threads = one wave per (b,h) row

typedef float f4 __attribute__((ext_vector_type(4)));

__global__ __launch_bounds__(256)
void skel_conv_kernel(const float* __restrict__ x, const float* __restrict__ wgt,
                      const int* __restrict__ dil_p, const int* __restrict__ step_p,
                      float* __restrict__ out, int B)
{
    const int dil  = dil_p[0];
    const int step = step_p[0];

    const int tid  = blockIdx.x * blockDim.x + threadIdx.x;
    const int lane = tid & (TPR - 1);          // == lane-in-wave; one wave spans a row
    const int h    = (tid / TPR) & (H - 1);
    const int b    = tid / (TPR * H);
    if (b >= B) return;
    const int w0 = lane * WT;

    float acc[COUT][WT];
    #pragma unroll
    for (int o = 0; o < COUT; ++o)
        #pragma unroll
        for (int j = 0; j < WT; ++j) acc[o][j] = 0.f;

    const size_t xbase = (size_t)b * CIN * H * W;

    if (dil == 1 && step == 0) {
        // Fast path: horizontal 3-tap conv. Each lane owns 4 consecutive w;
        // the +-1 taps come from own float4 + one element from neighbor lane.
        for (int c = 0; c < CIN; ++c) {
            const float* xr = x + xbase + (size_t)c * (H * W) + (size_t)h * W;
            f4 v = *(const f4*)(xr + w0);                 // coalesced, aligned
            float left  = __shfl_up(v.w, 1);              // x[w0-1]
            float right = __shfl_down(v.x, 1);            // x[w0+4]
            if (lane == 0)       left  = 0.f;             // zero padding
            if (lane == TPR - 1) right = 0.f;

            const float t0[WT] = {left, v.x, v.y, v.z};   // tap k=0 (off=-1)
            const float t1[WT] = {v.x,  v.y, v.z, v.w};   // tap k=1 (off= 0)
            const float t2[WT] = {v.y,  v.z, v.w, right}; // tap k=2 (off=+1)

            #pragma unroll
            for (int o = 0; o < COUT; ++o) {
                // uniform indices -> s_load; SGPR source folds into v_fmac_f32
                const float wk0 = wgt[(o * CIN + c) * KK + 0];
                const float wk1 = wgt[(o * CIN + c) * KK + 1];
                const float wk2 = wgt[(o * CIN + c) * KK + 2];
                #pragma unroll
                for (int j = 0; j < WT; ++j)
                    acc[o][j] += wk0 * t0[j] + wk1 * t1[j] + wk2 * t2[j];
            }
        }
    } else {
        // Generic path: clamped loads + select (never faults, handles any dil/step).
        for (int c = 0; c < CIN; ++c) {
            const float* xc = x + xbase + (size_t)c * (H * W);
            #pragma unroll
            for (int k = 0; k < KK; ++k) {
                const int off = k - KK / 2;
                const int hh  = h + off * step;
                const bool rowok = (hh >= 0) && (hh < H);
                const int hcl = hh < 0 ? 0 : (hh > H - 1 ? H - 1 : hh);
                float t[WT];
                #pragma unroll
                for (int j = 0; j < WT; ++j) {
                    const int ww  = w0 + j + off * dil;
                    const bool ok = rowok && (ww >= 0) && (ww < W);
                    const int wcl = ww < 0 ? 0 : (ww > W - 1 ? W - 1 : ww);
                    const float v = xc[(size_t)hcl * W + wcl];
                    t[j] = ok ? v : 0.f;
                }
                #pragma unroll
                for (int o = 0; o < COUT; ++o) {
                    const float wk = wgt[(o * CIN + c) * KK + k];
                    #pragma unroll
                    for (int j = 0; j < WT; ++j)
                        acc[o][j] += wk * t[j];
                }
            }
        }
    }

    float* orow = out + ((size_t)b * COUT * H + h) * W + w0;
    #pragma unroll
    for (int o = 0; o < COUT; ++o) {
        f4 r = {acc[o][0], acc[o][1], acc[o][2], acc[o][3]};
        *(f4*)(orow + (size_t)o * (H * W)) = r;            // coalesced, aligned
    }
}

extern "C" void kernel_launch(void* const* d_in, const int* in_sizes, int n_in,
                              void* d_out, int out_size, void* d_ws, size_t ws_size,
                              hipStream_t stream) {
    const float* x    = (const float*)d_in[0];
    const float* wgt  = (const float*)d_in[1];
    const int*   dil  = (const int*)d_in[2];
    const int*   step = (const int*)d_in[3];
    float*       out  = (float*)d_out;

    const int B = in_sizes[0] / (CIN * H * W);
    const int total = B * H * TPR;               // one thread per 4 output w's
    const int block = 256;
    const int grid  = (total + block - 1) / block;

    skel_conv_kernel<<<grid, block, 0, stream>>>(x, wgt, dil, step, out, B);
}